// Round 5
// baseline (639.313 us; speedup 1.0000x reference)
//
#include <hip/hip_runtime.h>
#include <hip/hip_bf16.h>

// OddOneOutNet forward: B=1024, N=5, H=W=64, D=24, NK=6, META=16.
// Inputs fp32, OUTPUT fp32 (reference returns jnp.float32 — harness reads
// d_out as float*), math fp32.
// SINGLE fused kernel: one block (256 thr) per batch row. 5 CNN panels run
// sequentially into LDS ph[5][16]; head phase follows in the same block.
// LDS: union{ CNN bufs 50,192 B | head scratch 15,200 B } + weights 10,800 B
//      + ph 320 B + red 256 B = 61,568 B  (< 64 KiB static cap).

struct CnnBufs {
    float bufA[66 * 66];      // padded input, later padded h2 [12][18][18]
    float h1[8 * 32 * 32];    // conv1+pool output, unpadded
};
struct HeadBufs {
    float mt[5][16];
    float zc[5][20], zmh[5][12], zm[5][12];
    float p1h[5][24], h0[5][24];
    float archl[5][6], q[5][6];
    float center[5][24], coord[5][24], x0[5][24];
    float qkv[5][72];
    float attn[2][5][5];
    float amix[5][24], aout[5][24], x1[5][24];
    float ffh[5][48], ff2o[5][24], hset[5][24], mo[5][24];
    float pq[20], pdist[20];
    float relh[20][10], relo[20][10];
    float rmean[5][10], rmax[5][10];
    float sfeat[5][146];
    float s1h[5][40];
};
union SMemU { CnnBufs cnn; HeadBufs head; };

__global__ __launch_bounds__(256)
void fused_kernel(const float* __restrict__ xin,      // [B,5,64,64]
                  const float* __restrict__ meta,     // [B,5,16]
                  const float* __restrict__ c1w, const float* __restrict__ c1b,
                  const float* __restrict__ c2w, const float* __restrict__ c2b,
                  const float* __restrict__ c3w, const float* __restrict__ c3b,
                  const float* __restrict__ enc_fc_w, const float* __restrict__ enc_fc_b,
                  const float* __restrict__ m1_w, const float* __restrict__ m1_b,
                  const float* __restrict__ m2_w, const float* __restrict__ m2_b,
                  const float* __restrict__ p1_w, const float* __restrict__ p1_b,
                  const float* __restrict__ p2_w, const float* __restrict__ p2_b,
                  const float* __restrict__ centers,
                  const float* __restrict__ arch_w, const float* __restrict__ arch_b,
                  const float* __restrict__ in_proj_w, const float* __restrict__ in_proj_b,
                  const float* __restrict__ out_proj_w, const float* __restrict__ out_proj_b,
                  const float* __restrict__ ln1_g, const float* __restrict__ ln1_b,
                  const float* __restrict__ ff1_w, const float* __restrict__ ff1_b,
                  const float* __restrict__ ff2_w, const float* __restrict__ ff2_b,
                  const float* __restrict__ ln2_g, const float* __restrict__ ln2_b,
                  const float* __restrict__ rel1_w, const float* __restrict__ rel1_b,
                  const float* __restrict__ rel2_w, const float* __restrict__ rel2_b,
                  const float* __restrict__ s1_w, const float* __restrict__ s1_b,
                  const float* __restrict__ s2_w, const float* __restrict__ s2_b,
                  float* __restrict__ out, int q_off)
{
    __shared__ SMemU sm;
    __shared__ float w1[72], b1s[8];
    __shared__ float w2[864], b2s[12];
    __shared__ float w3[1728], b3s[16];
    __shared__ float ph[5][16];
    __shared__ float red[64];

    const int tid = threadIdx.x;
    const int b = blockIdx.x;

    // ---- stage conv weights once ----
    for (int i = tid; i < 72; i += 256) w1[i] = c1w[i];
    if (tid < 8)  b1s[tid] = c1b[tid];
    for (int i = tid; i < 864; i += 256) w2[i] = c2w[i];
    if (tid < 12) b2s[tid] = c2b[tid];
    for (int i = tid; i < 1728; i += 256) w3[i] = c3w[i];
    if (tid < 16) b3s[tid] = c3b[tid];

    // =====================================================================
    // Phase A: 5 CNN panels sequentially -> ph[5][16]
    // =====================================================================
    float (&bufA)[66 * 66] = sm.cnn.bufA;
    float (&h1)[8 * 32 * 32] = sm.cnn.h1;

    for (int n = 0; n < 5; ++n) {
        // zero padded input buffer (also erases previous panel's h2)
        __syncthreads();
        for (int i = tid; i < 66 * 66; i += 256) bufA[i] = 0.0f;
        __syncthreads();

        // load 64x64 panel (float4)
        {
            const float4* xv = (const float4*)(xin + ((size_t)b * 5 + n) * 4096);
            for (int i = tid; i < 1024; i += 256) {
                float4 u = xv[i];
                int base = i << 2;
                int y = base >> 6, x = base & 63;
                float* dst = &bufA[(y + 1) * 66 + (x + 1)];
                dst[0] = u.x; dst[1] = u.y; dst[2] = u.z; dst[3] = u.w;
            }
        }
        __syncthreads();

        // conv1(1->8,3x3,SAME)+relu+maxpool2 -> h1 [8][32][32]
        for (int p = 0; p < 4; ++p) {
            int pos = tid + (p << 8);
            int py = pos >> 5, px = pos & 31;
            float patch[4][4];
            #pragma unroll
            for (int dy = 0; dy < 4; ++dy)
                #pragma unroll
                for (int dx = 0; dx < 4; ++dx)
                    patch[dy][dx] = bufA[(2 * py + dy) * 66 + (2 * px + dx)];
            #pragma unroll
            for (int c = 0; c < 8; ++c) {
                float m = -1e30f;
                #pragma unroll
                for (int ay = 0; ay < 2; ++ay)
                    #pragma unroll
                    for (int ax = 0; ax < 2; ++ax) {
                        float acc = b1s[c];
                        #pragma unroll
                        for (int ky = 0; ky < 3; ++ky)
                            #pragma unroll
                            for (int kx = 0; kx < 3; ++kx)
                                acc += patch[ay + ky][ax + kx] * w1[c * 9 + ky * 3 + kx];
                        m = fmaxf(m, acc);
                    }
                h1[c * 1024 + py * 32 + px] = fmaxf(m, 0.0f);
            }
        }
        __syncthreads();

        // re-zero bufA region for padded h2 [12][18][18]
        for (int i = tid; i < 12 * 18 * 18; i += 256) bufA[i] = 0.0f;
        __syncthreads();

        // conv2(8->12)+relu+maxpool2 -> bufA interior [12][16][16]
        {
            int py = tid >> 4, px = tid & 15;
            float acc[12][4];
            #pragma unroll
            for (int c = 0; c < 12; ++c) {
                float bb = b2s[c];
                acc[c][0] = bb; acc[c][1] = bb; acc[c][2] = bb; acc[c][3] = bb;
            }
            for (int ci = 0; ci < 8; ++ci) {
                float patch[4][4];
                #pragma unroll
                for (int dy = 0; dy < 4; ++dy) {
                    int r = 2 * py - 1 + dy;
                    #pragma unroll
                    for (int dx = 0; dx < 4; ++dx) {
                        int cc = 2 * px - 1 + dx;
                        patch[dy][dx] = (r >= 0 && r < 32 && cc >= 0 && cc < 32)
                                      ? h1[ci * 1024 + r * 32 + cc] : 0.0f;
                    }
                }
                #pragma unroll
                for (int c = 0; c < 12; ++c) {
                    const float* wp = &w2[(c * 8 + ci) * 9];
                    #pragma unroll
                    for (int ay = 0; ay < 2; ++ay)
                        #pragma unroll
                        for (int ax = 0; ax < 2; ++ax) {
                            float a = acc[c][ay * 2 + ax];
                            #pragma unroll
                            for (int ky = 0; ky < 3; ++ky)
                                #pragma unroll
                                for (int kx = 0; kx < 3; ++kx)
                                    a += patch[ay + ky][ax + kx] * wp[ky * 3 + kx];
                            acc[c][ay * 2 + ax] = a;
                        }
                }
            }
            #pragma unroll
            for (int c = 0; c < 12; ++c) {
                float m = fmaxf(fmaxf(acc[c][0], acc[c][1]), fmaxf(acc[c][2], acc[c][3]));
                bufA[c * 324 + (py + 1) * 18 + (px + 1)] = fmaxf(m, 0.0f);
            }
        }
        __syncthreads();

        // conv3(12->16)+relu+mean -> ph[n][16]
        {
            int y = tid >> 4, x = tid & 15;
            float acc[16];
            #pragma unroll
            for (int c = 0; c < 16; ++c) acc[c] = b3s[c];
            for (int ci = 0; ci < 12; ++ci) {
                float patch[3][3];
                #pragma unroll
                for (int dy = 0; dy < 3; ++dy)
                    #pragma unroll
                    for (int dx = 0; dx < 3; ++dx)
                        patch[dy][dx] = bufA[ci * 324 + (y + dy) * 18 + (x + dx)];
                #pragma unroll
                for (int c = 0; c < 16; ++c) {
                    const float* wp = &w3[(c * 12 + ci) * 9];
                    float a = acc[c];
                    #pragma unroll
                    for (int ky = 0; ky < 3; ++ky)
                        #pragma unroll
                        for (int kx = 0; kx < 3; ++kx)
                            a += patch[ky][kx] * wp[ky * 3 + kx];
                    acc[c] = a;
                }
            }
            int lane = tid & 63, wave = tid >> 6;
            #pragma unroll
            for (int c = 0; c < 16; ++c) {
                float v = fmaxf(acc[c], 0.0f);
                v += __shfl_down(v, 32);
                v += __shfl_down(v, 16);
                v += __shfl_down(v, 8);
                v += __shfl_down(v, 4);
                v += __shfl_down(v, 2);
                v += __shfl_down(v, 1);
                if (lane == 0) red[c * 4 + wave] = v;
            }
            __syncthreads();
            if (tid < 16) {
                float s = red[tid * 4] + red[tid * 4 + 1] + red[tid * 4 + 2] + red[tid * 4 + 3];
                ph[n][tid] = s * (1.0f / 256.0f);
            }
        }
    }
    __syncthreads();

    // =====================================================================
    // Phase B: head (CNN buffers dead; union flips to head scratch)
    // =====================================================================
    HeadBufs& H = sm.head;

    for (int i = tid; i < 80; i += 256) ((float*)H.mt)[i] = meta[(size_t)b * 80 + i];
    __syncthreads();

    // z_cen = enc_fc(ph); zmh = relu(m1 @ meta)
    for (int idx = tid; idx < 100; idx += 256) {
        int n = idx / 20, o = idx % 20;
        float a = enc_fc_b[o];
        #pragma unroll
        for (int k = 0; k < 16; ++k) a += ph[n][k] * enc_fc_w[o * 16 + k];
        H.zc[n][o] = a;
    }
    for (int idx = tid; idx < 60; idx += 256) {
        int n = idx / 12, o = idx % 12;
        float a = m1_b[o];
        #pragma unroll
        for (int k = 0; k < 16; ++k) a += H.mt[n][k] * m1_w[o * 16 + k];
        H.zmh[n][o] = fmaxf(a, 0.0f);
    }
    __syncthreads();
    for (int idx = tid; idx < 60; idx += 256) {
        int n = idx / 12, o = idx % 12;
        float a = m2_b[o];
        #pragma unroll
        for (int k = 0; k < 12; ++k) a += H.zmh[n][k] * m2_w[o * 12 + k];
        H.zm[n][o] = a;
    }
    __syncthreads();
    for (int idx = tid; idx < 120; idx += 256) {
        int n = idx / 24, o = idx % 24;
        float a = p1_b[o];
        #pragma unroll
        for (int k = 0; k < 20; ++k) a += H.zc[n][k] * p1_w[o * 32 + k];
        #pragma unroll
        for (int k = 0; k < 12; ++k) a += H.zm[n][k] * p1_w[o * 32 + 20 + k];
        H.p1h[n][o] = fmaxf(a, 0.0f);
    }
    __syncthreads();
    for (int idx = tid; idx < 120; idx += 256) {
        int n = idx / 24, o = idx % 24;
        float a = p2_b[o];
        #pragma unroll
        for (int k = 0; k < 24; ++k) a += H.p1h[n][k] * p2_w[o * 24 + k];
        H.h0[n][o] = a;
    }
    __syncthreads();
    for (int idx = tid; idx < 30; idx += 256) {
        int n = idx / 6, o = idx % 6;
        float a = arch_b[o];
        #pragma unroll
        for (int k = 0; k < 24; ++k) a += H.h0[n][k] * arch_w[o * 24 + k];
        H.archl[n][o] = a;
    }
    __syncthreads();
    if (tid < 5) {
        int n = tid;
        float m = H.archl[n][0];
        #pragma unroll
        for (int k = 1; k < 6; ++k) m = fmaxf(m, H.archl[n][k]);
        float e[6], s = 0.0f;
        #pragma unroll
        for (int k = 0; k < 6; ++k) { e[k] = __expf(H.archl[n][k] - m); s += e[k]; }
        float inv = 1.0f / s;
        #pragma unroll
        for (int k = 0; k < 6; ++k) H.q[n][k] = e[k] * inv;
    }
    __syncthreads();
    for (int idx = tid; idx < 120; idx += 256) {
        int n = idx / 24, d = idx % 24;
        float a = 0.0f;
        #pragma unroll
        for (int k = 0; k < 6; ++k) a += H.q[n][k] * centers[k * 24 + d];
        H.center[n][d] = a;
        H.coord[n][d] = H.h0[n][d] - a;
        H.x0[n][d] = H.h0[n][d] + a;
    }
    __syncthreads();
    for (int idx = tid; idx < 360; idx += 256) {
        int n = idx / 72, o = idx % 72;
        float a = in_proj_b[o];
        #pragma unroll
        for (int k = 0; k < 24; ++k) a += H.x0[n][k] * in_proj_w[o * 24 + k];
        H.qkv[n][o] = a;
    }
    __syncthreads();
    if (tid < 10) {
        int h = tid / 5, i = tid % 5;
        const float scale = 0.28867513459481287f;  // 1/sqrt(12)
        float sc[5], m = -1e30f;
        for (int j = 0; j < 5; ++j) {
            float a = 0.0f;
            #pragma unroll
            for (int d = 0; d < 12; ++d) a += H.qkv[i][h * 12 + d] * H.qkv[j][24 + h * 12 + d];
            sc[j] = a * scale;
            m = fmaxf(m, sc[j]);
        }
        float s = 0.0f;
        #pragma unroll
        for (int j = 0; j < 5; ++j) { sc[j] = __expf(sc[j] - m); s += sc[j]; }
        float inv = 1.0f / s;
        #pragma unroll
        for (int j = 0; j < 5; ++j) H.attn[h][i][j] = sc[j] * inv;
    }
    __syncthreads();
    for (int idx = tid; idx < 120; idx += 256) {
        int i = idx / 24, o = idx % 24;
        int h = o / 12, d = o % 12;
        float a = 0.0f;
        #pragma unroll
        for (int j = 0; j < 5; ++j) a += H.attn[h][i][j] * H.qkv[j][48 + h * 12 + d];
        H.amix[i][o] = a;
    }
    __syncthreads();
    for (int idx = tid; idx < 120; idx += 256) {
        int n = idx / 24, o = idx % 24;
        float a = out_proj_b[o];
        #pragma unroll
        for (int k = 0; k < 24; ++k) a += H.amix[n][k] * out_proj_w[o * 24 + k];
        H.aout[n][o] = H.x0[n][o] + a;
    }
    __syncthreads();
    if (tid < 5) {
        int n = tid;
        float m = 0.0f;
        #pragma unroll
        for (int k = 0; k < 24; ++k) m += H.aout[n][k];
        m *= (1.0f / 24.0f);
        float v = 0.0f;
        #pragma unroll
        for (int k = 0; k < 24; ++k) { float d = H.aout[n][k] - m; v += d * d; }
        v *= (1.0f / 24.0f);
        float inv = 1.0f / sqrtf(v + 1e-5f);
        #pragma unroll
        for (int k = 0; k < 24; ++k)
            H.x1[n][k] = (H.aout[n][k] - m) * inv * ln1_g[k] + ln1_b[k];
    }
    __syncthreads();
    for (int idx = tid; idx < 240; idx += 256) {
        int n = idx / 48, o = idx % 48;
        float a = ff1_b[o];
        #pragma unroll
        for (int k = 0; k < 24; ++k) a += H.x1[n][k] * ff1_w[o * 24 + k];
        H.ffh[n][o] = fmaxf(a, 0.0f);
    }
    __syncthreads();
    for (int idx = tid; idx < 120; idx += 256) {
        int n = idx / 24, o = idx % 24;
        float a = ff2_b[o];
        #pragma unroll
        for (int k = 0; k < 48; ++k) a += H.ffh[n][k] * ff2_w[o * 48 + k];
        H.ff2o[n][o] = H.x1[n][o] + a;
    }
    __syncthreads();
    if (tid < 5) {
        int n = tid;
        float m = 0.0f;
        #pragma unroll
        for (int k = 0; k < 24; ++k) m += H.ff2o[n][k];
        m *= (1.0f / 24.0f);
        float v = 0.0f;
        #pragma unroll
        for (int k = 0; k < 24; ++k) { float d = H.ff2o[n][k] - m; v += d * d; }
        v *= (1.0f / 24.0f);
        float inv = 1.0f / sqrtf(v + 1e-5f);
        #pragma unroll
        for (int k = 0; k < 24; ++k)
            H.hset[n][k] = (H.ff2o[n][k] - m) * inv * ln2_g[k] + ln2_b[k];
    }
    __syncthreads();
    for (int idx = tid; idx < 120; idx += 256) {
        int n = idx / 24, d = idx % 24;
        float s = H.hset[0][d] + H.hset[1][d] + H.hset[2][d] + H.hset[3][d] + H.hset[4][d];
        H.mo[n][d] = (s - H.hset[n][d]) * 0.25f;
    }
    if (tid < 20) {
        int i = tid / 4, jj = tid % 4;
        int j = jj + (jj >= i ? 1 : 0);
        float qo = 0.0f;
        #pragma unroll
        for (int k = 0; k < 6; ++k) qo += H.q[i][k] * H.q[j][k];
        H.pq[tid] = qo;
        float d2 = 0.0f;
        #pragma unroll
        for (int k = 0; k < 24; ++k) { float d = H.coord[i][k] - H.coord[j][k]; d2 += d * d; }
        H.pdist[tid] = (d2 > 0.0f) ? sqrtf(d2) : 0.0f;
    }
    __syncthreads();
    for (int idx = tid; idx < 200; idx += 256) {
        int p = idx / 10, c = idx % 10;
        int i = p / 4, jj = p % 4;
        int j = jj + (jj >= i ? 1 : 0);
        float a = rel1_b[c];
        const float* wr = rel1_w + c * 74;
        #pragma unroll
        for (int k = 0; k < 24; ++k) a += H.hset[i][k] * wr[k];
        #pragma unroll
        for (int k = 0; k < 24; ++k) a += H.hset[j][k] * wr[24 + k];
        #pragma unroll
        for (int k = 0; k < 24; ++k) a += fabsf(H.coord[i][k] - H.coord[j][k]) * wr[48 + k];
        a += H.pq[p] * wr[72];
        a += H.pdist[p] * wr[73];
        H.relh[p][c] = fmaxf(a, 0.0f);
    }
    __syncthreads();
    for (int idx = tid; idx < 200; idx += 256) {
        int p = idx / 10, c = idx % 10;
        float a = rel2_b[c];
        #pragma unroll
        for (int k = 0; k < 10; ++k) a += H.relh[p][k] * rel2_w[c * 10 + k];
        H.relo[p][c] = fmaxf(a, 0.0f);
    }
    __syncthreads();
    for (int idx = tid; idx < 50; idx += 256) {
        int i = idx / 10, c = idx % 10;
        float s = 0.0f, m = -1e30f;
        #pragma unroll
        for (int jj = 0; jj < 4; ++jj) {
            float v = H.relo[i * 4 + jj][c];
            s += v; m = fmaxf(m, v);
        }
        H.rmean[i][c] = s * 0.25f;
        H.rmax[i][c] = m;
    }
    __syncthreads();
    for (int idx = tid; idx < 730; idx += 256) {
        int n = idx / 146, k = idx % 146;
        float v;
        if (k < 24)       v = H.h0[n][k];
        else if (k < 48)  v = H.hset[n][k - 24];
        else if (k < 72)  v = H.center[n][k - 48];
        else if (k < 96)  v = H.coord[n][k - 72];
        else if (k < 120) v = fabsf(H.hset[n][k - 96] - H.mo[n][k - 96]);
        else if (k < 130) v = H.rmean[n][k - 120];
        else if (k < 140) v = H.rmax[n][k - 130];
        else              v = H.q[n][k - 140];
        H.sfeat[n][k] = v;
    }
    __syncthreads();
    for (int idx = tid; idx < 200; idx += 256) {
        int n = idx / 40, o = idx % 40;
        float a = s1_b[o];
        for (int k = 0; k < 146; ++k) a += H.sfeat[n][k] * s1_w[o * 146 + k];
        H.s1h[n][o] = fmaxf(a, 0.0f);
    }
    __syncthreads();
    if (tid < 5) {
        int n = tid;
        float a = s2_b[0];
        #pragma unroll
        for (int k = 0; k < 40; ++k) a += H.s1h[n][k] * s2_w[k];
        out[(size_t)b * 5 + n] = a;                       // fp32 output
    }
    if (tid < 30) {
        out[q_off + (size_t)b * 30 + tid] = H.q[tid / 6][tid % 6];  // fp32 output
    }
}

extern "C" void kernel_launch(void* const* d_in, const int* in_sizes, int n_in,
                              void* d_out, int out_size, void* d_ws, size_t ws_size,
                              hipStream_t stream) {
    const int BN = in_sizes[0] / (64 * 64);   // B*5
    const int Bb = BN / 5;                    // B

    fused_kernel<<<Bb, 256, 0, stream>>>(
        (const float*)d_in[0], (const float*)d_in[1],
        (const float*)d_in[2], (const float*)d_in[3],
        (const float*)d_in[4], (const float*)d_in[5],
        (const float*)d_in[6], (const float*)d_in[7],
        (const float*)d_in[8], (const float*)d_in[9],
        (const float*)d_in[10], (const float*)d_in[11],
        (const float*)d_in[12], (const float*)d_in[13],
        (const float*)d_in[14], (const float*)d_in[15],
        (const float*)d_in[16], (const float*)d_in[17],
        (const float*)d_in[18],
        (const float*)d_in[19], (const float*)d_in[20],
        (const float*)d_in[21], (const float*)d_in[22],
        (const float*)d_in[23], (const float*)d_in[24],
        (const float*)d_in[25], (const float*)d_in[26],
        (const float*)d_in[27], (const float*)d_in[28],
        (const float*)d_in[29], (const float*)d_in[30],
        (const float*)d_in[31], (const float*)d_in[32],
        (const float*)d_in[33], (const float*)d_in[34],
        (const float*)d_in[35], (const float*)d_in[36],
        (const float*)d_in[37], (const float*)d_in[38],
        (const float*)d_in[39], (const float*)d_in[40],
        (float*)d_out, BN);
}

// Round 6
// 476.791 us; speedup vs baseline: 1.3409x; 1.3409x over previous
//
#include <hip/hip_runtime.h>
#include <hip/hip_bf16.h>

// OddOneOutNet forward: B=1024, N=5, H=W=64, D=24, NK=6, META=16.
// Inputs fp32, output fp32, math fp32.
// Kernel A: per-panel TinyCNN (grid B*N=5120, 256 thr). LDS 52.5 KB -> 3 blocks/CU
//   (round-5 fused version was 61.9 KB -> 2 blocks/CU, VALUBusy 56%).
//   Conv weights read from global via uniform scalar loads (no LDS staging).
// Kernel B: per-batch-row head (grid B=1024, 64 thr), proven formulas.

// ---------------------------------------------------------------------------
// Kernel A: one block per panel.
// LDS: bufA[66*66]=17,424 B (padded input, later h2 [12][18][18])
//      h1[8][32][34]=34,816 B (conv1+pool out, x-padded: col 0 and 33 are zero)
//      red aliased into h1 (dead by reduce time). Total 52,240 B.
// ---------------------------------------------------------------------------
__global__ __launch_bounds__(256)
void cnn_panel_kernel(const float* __restrict__ xin,   // [BN,64,64]
                      const float* __restrict__ c1w, const float* __restrict__ c1b,
                      const float* __restrict__ c2w, const float* __restrict__ c2b,
                      const float* __restrict__ c3w, const float* __restrict__ c3b,
                      float* __restrict__ pooled)      // [BN,16] (ws)
{
    __shared__ float bufA[66 * 66];
    __shared__ float h1[8 * 32 * 34];   // [c][y][x+1], cols 0..33, stride 34

    const int tid = threadIdx.x;
    const int img = blockIdx.x;

    // ---- zero padded input buffer + h1 column pads ----
    for (int i = tid; i < 66 * 66; i += 256) bufA[i] = 0.0f;
    for (int i = tid; i < 512; i += 256) {
        int c = i >> 6, rest = i & 63;
        int y = rest >> 1, side = rest & 1;
        h1[c * 1088 + y * 34 + side * 33] = 0.0f;
    }
    __syncthreads();

    // ---- load 64x64 panel into padded bufA (float4) ----
    {
        const float4* xv = (const float4*)(xin + (size_t)img * 4096);
        for (int i = tid; i < 1024; i += 256) {
            float4 u = xv[i];
            int base = i << 2;
            int y = base >> 6, x = base & 63;
            float* dst = &bufA[(y + 1) * 66 + (x + 1)];
            dst[0] = u.x; dst[1] = u.y; dst[2] = u.z; dst[3] = u.w;
        }
    }
    __syncthreads();

    // ---- conv1(1->8,3x3,SAME)+relu+maxpool2 -> h1 interior ----
    for (int p = 0; p < 4; ++p) {
        int pos = tid + (p << 8);
        int py = pos >> 5, px = pos & 31;
        float patch[4][4];
        #pragma unroll
        for (int dy = 0; dy < 4; ++dy)
            #pragma unroll
            for (int dx = 0; dx < 4; ++dx)
                patch[dy][dx] = bufA[(2 * py + dy) * 66 + (2 * px + dx)];
        #pragma unroll
        for (int c = 0; c < 8; ++c) {
            float bb = c1b[c];
            float m = -1e30f;
            #pragma unroll
            for (int ay = 0; ay < 2; ++ay)
                #pragma unroll
                for (int ax = 0; ax < 2; ++ax) {
                    float acc = bb;
                    #pragma unroll
                    for (int ky = 0; ky < 3; ++ky)
                        #pragma unroll
                        for (int kx = 0; kx < 3; ++kx)
                            acc += patch[ay + ky][ax + kx] * c1w[c * 9 + ky * 3 + kx];
                    m = fmaxf(m, acc);
                }
            h1[c * 1088 + py * 34 + (px + 1)] = fmaxf(m, 0.0f);
        }
    }
    __syncthreads();

    // ---- zero h2 region (bufA[0..3887]) ----
    for (int i = tid; i < 12 * 18 * 18; i += 256) bufA[i] = 0.0f;
    __syncthreads();

    // ---- conv2(8->12)+relu+maxpool2 -> bufA interior [12][16][16] ----
    {
        int py = tid >> 4, px = tid & 15;
        float acc[12][4];
        #pragma unroll
        for (int c = 0; c < 12; ++c) {
            float bb = c2b[c];
            acc[c][0] = bb; acc[c][1] = bb; acc[c][2] = bb; acc[c][3] = bb;
        }
        for (int ci = 0; ci < 8; ++ci) {
            float patch[4][4];
            #pragma unroll
            for (int dy = 0; dy < 4; ++dy) {
                int r = 2 * py - 1 + dy;
                bool okr = (r >= 0) && (r < 32);
                const float* row = &h1[ci * 1088 + r * 34 + 2 * px]; // col idx (2px-1+dx)+1
                #pragma unroll
                for (int dx = 0; dx < 4; ++dx)
                    patch[dy][dx] = okr ? row[dx] : 0.0f;
            }
            #pragma unroll
            for (int c = 0; c < 12; ++c) {
                const float* wp = &c2w[(c * 8 + ci) * 9];
                #pragma unroll
                for (int ay = 0; ay < 2; ++ay)
                    #pragma unroll
                    for (int ax = 0; ax < 2; ++ax) {
                        float a = acc[c][ay * 2 + ax];
                        #pragma unroll
                        for (int ky = 0; ky < 3; ++ky)
                            #pragma unroll
                            for (int kx = 0; kx < 3; ++kx)
                                a += patch[ay + ky][ax + kx] * wp[ky * 3 + kx];
                        acc[c][ay * 2 + ax] = a;
                    }
            }
        }
        #pragma unroll
        for (int c = 0; c < 12; ++c) {
            float m = fmaxf(fmaxf(acc[c][0], acc[c][1]), fmaxf(acc[c][2], acc[c][3]));
            bufA[c * 324 + (py + 1) * 18 + (px + 1)] = fmaxf(m, 0.0f);
        }
    }
    __syncthreads();

    // ---- conv3(12->16)+relu+mean -> pooled[img][16] ----
    {
        int y = tid >> 4, x = tid & 15;
        float acc[16];
        #pragma unroll
        for (int c = 0; c < 16; ++c) acc[c] = c3b[c];
        for (int ci = 0; ci < 12; ++ci) {
            float patch[3][3];
            #pragma unroll
            for (int dy = 0; dy < 3; ++dy)
                #pragma unroll
                for (int dx = 0; dx < 3; ++dx)
                    patch[dy][dx] = bufA[ci * 324 + (y + dy) * 18 + (x + dx)];
            #pragma unroll
            for (int c = 0; c < 16; ++c) {
                const float* wp = &c3w[(c * 12 + ci) * 9];
                float a = acc[c];
                #pragma unroll
                for (int ky = 0; ky < 3; ++ky)
                    #pragma unroll
                    for (int kx = 0; kx < 3; ++kx)
                        a += patch[ky][kx] * wp[ky * 3 + kx];
                acc[c] = a;
            }
        }
        float* red = h1;  // h1 is dead now
        int lane = tid & 63, wave = tid >> 6;
        #pragma unroll
        for (int c = 0; c < 16; ++c) {
            float v = fmaxf(acc[c], 0.0f);
            v += __shfl_down(v, 32);
            v += __shfl_down(v, 16);
            v += __shfl_down(v, 8);
            v += __shfl_down(v, 4);
            v += __shfl_down(v, 2);
            v += __shfl_down(v, 1);
            if (lane == 0) red[c * 4 + wave] = v;
        }
        __syncthreads();
        if (tid < 16) {
            float s = red[tid * 4] + red[tid * 4 + 1] + red[tid * 4 + 2] + red[tid * 4 + 3];
            pooled[(size_t)img * 16 + tid] = s * (1.0f / 256.0f);
        }
    }
}

// ---------------------------------------------------------------------------
// Kernel B: head, one 64-thread block per batch row.
// ---------------------------------------------------------------------------
__global__ __launch_bounds__(64)
void head_kernel(const float* __restrict__ pooled,    // [B*5,16]
                 const float* __restrict__ meta,      // [B,5,16]
                 const float* __restrict__ enc_fc_w, const float* __restrict__ enc_fc_b,
                 const float* __restrict__ m1_w, const float* __restrict__ m1_b,
                 const float* __restrict__ m2_w, const float* __restrict__ m2_b,
                 const float* __restrict__ p1_w, const float* __restrict__ p1_b,
                 const float* __restrict__ p2_w, const float* __restrict__ p2_b,
                 const float* __restrict__ centers,
                 const float* __restrict__ arch_w, const float* __restrict__ arch_b,
                 const float* __restrict__ in_proj_w, const float* __restrict__ in_proj_b,
                 const float* __restrict__ out_proj_w, const float* __restrict__ out_proj_b,
                 const float* __restrict__ ln1_g, const float* __restrict__ ln1_b,
                 const float* __restrict__ ff1_w, const float* __restrict__ ff1_b,
                 const float* __restrict__ ff2_w, const float* __restrict__ ff2_b,
                 const float* __restrict__ ln2_g, const float* __restrict__ ln2_b,
                 const float* __restrict__ rel1_w, const float* __restrict__ rel1_b,
                 const float* __restrict__ rel2_w, const float* __restrict__ rel2_b,
                 const float* __restrict__ s1_w, const float* __restrict__ s1_b,
                 const float* __restrict__ s2_w, const float* __restrict__ s2_b,
                 float* __restrict__ out, int q_off)
{
    const int b = blockIdx.x;
    const int tid = threadIdx.x;

    __shared__ float ph[5][16], mt[5][16];
    __shared__ float zc[5][20], zmh[5][12], zm[5][12];
    __shared__ float p1h[5][24], h0[5][24];
    __shared__ float archl[5][6], q[5][6];
    __shared__ float center[5][24], coord[5][24], x0[5][24];
    __shared__ float qkv[5][72];
    __shared__ float attn[2][5][5];
    __shared__ float amix[5][24], aout[5][24], x1[5][24];
    __shared__ float ffh[5][48], ff2o[5][24], hset[5][24], mo[5][24];
    __shared__ float pq[20], pdist[20];
    __shared__ float relh[20][10], relo[20][10];
    __shared__ float rmean[5][10], rmax[5][10];
    __shared__ float sfeat[5][146];
    __shared__ float s1h[5][40];

    for (int i = tid; i < 80; i += 64) ((float*)ph)[i] = pooled[(size_t)b * 80 + i];
    for (int i = tid; i < 80; i += 64) ((float*)mt)[i] = meta[(size_t)b * 80 + i];
    __syncthreads();

    for (int idx = tid; idx < 100; idx += 64) {
        int n = idx / 20, o = idx % 20;
        float a = enc_fc_b[o];
        #pragma unroll
        for (int k = 0; k < 16; ++k) a += ph[n][k] * enc_fc_w[o * 16 + k];
        zc[n][o] = a;
    }
    for (int idx = tid; idx < 60; idx += 64) {
        int n = idx / 12, o = idx % 12;
        float a = m1_b[o];
        #pragma unroll
        for (int k = 0; k < 16; ++k) a += mt[n][k] * m1_w[o * 16 + k];
        zmh[n][o] = fmaxf(a, 0.0f);
    }
    __syncthreads();
    for (int idx = tid; idx < 60; idx += 64) {
        int n = idx / 12, o = idx % 12;
        float a = m2_b[o];
        #pragma unroll
        for (int k = 0; k < 12; ++k) a += zmh[n][k] * m2_w[o * 12 + k];
        zm[n][o] = a;
    }
    __syncthreads();
    for (int idx = tid; idx < 120; idx += 64) {
        int n = idx / 24, o = idx % 24;
        float a = p1_b[o];
        #pragma unroll
        for (int k = 0; k < 20; ++k) a += zc[n][k] * p1_w[o * 32 + k];
        #pragma unroll
        for (int k = 0; k < 12; ++k) a += zm[n][k] * p1_w[o * 32 + 20 + k];
        p1h[n][o] = fmaxf(a, 0.0f);
    }
    __syncthreads();
    for (int idx = tid; idx < 120; idx += 64) {
        int n = idx / 24, o = idx % 24;
        float a = p2_b[o];
        #pragma unroll
        for (int k = 0; k < 24; ++k) a += p1h[n][k] * p2_w[o * 24 + k];
        h0[n][o] = a;
    }
    __syncthreads();
    for (int idx = tid; idx < 30; idx += 64) {
        int n = idx / 6, o = idx % 6;
        float a = arch_b[o];
        #pragma unroll
        for (int k = 0; k < 24; ++k) a += h0[n][k] * arch_w[o * 24 + k];
        archl[n][o] = a;
    }
    __syncthreads();
    if (tid < 5) {
        int n = tid;
        float m = archl[n][0];
        #pragma unroll
        for (int k = 1; k < 6; ++k) m = fmaxf(m, archl[n][k]);
        float e[6], s = 0.0f;
        #pragma unroll
        for (int k = 0; k < 6; ++k) { e[k] = __expf(archl[n][k] - m); s += e[k]; }
        float inv = 1.0f / s;
        #pragma unroll
        for (int k = 0; k < 6; ++k) q[n][k] = e[k] * inv;
    }
    __syncthreads();
    for (int idx = tid; idx < 120; idx += 64) {
        int n = idx / 24, d = idx % 24;
        float a = 0.0f;
        #pragma unroll
        for (int k = 0; k < 6; ++k) a += q[n][k] * centers[k * 24 + d];
        center[n][d] = a;
        coord[n][d] = h0[n][d] - a;
        x0[n][d] = h0[n][d] + a;
    }
    __syncthreads();
    for (int idx = tid; idx < 360; idx += 64) {
        int n = idx / 72, o = idx % 72;
        float a = in_proj_b[o];
        #pragma unroll
        for (int k = 0; k < 24; ++k) a += x0[n][k] * in_proj_w[o * 24 + k];
        qkv[n][o] = a;
    }
    __syncthreads();
    if (tid < 10) {
        int h = tid / 5, i = tid % 5;
        const float scale = 0.28867513459481287f;  // 1/sqrt(12)
        float sc[5], m = -1e30f;
        for (int j = 0; j < 5; ++j) {
            float a = 0.0f;
            #pragma unroll
            for (int d = 0; d < 12; ++d) a += qkv[i][h * 12 + d] * qkv[j][24 + h * 12 + d];
            sc[j] = a * scale;
            m = fmaxf(m, sc[j]);
        }
        float s = 0.0f;
        #pragma unroll
        for (int j = 0; j < 5; ++j) { sc[j] = __expf(sc[j] - m); s += sc[j]; }
        float inv = 1.0f / s;
        #pragma unroll
        for (int j = 0; j < 5; ++j) attn[h][i][j] = sc[j] * inv;
    }
    __syncthreads();
    for (int idx = tid; idx < 120; idx += 64) {
        int i = idx / 24, o = idx % 24;
        int h = o / 12, d = o % 12;
        float a = 0.0f;
        #pragma unroll
        for (int j = 0; j < 5; ++j) a += attn[h][i][j] * qkv[j][48 + h * 12 + d];
        amix[i][o] = a;
    }
    __syncthreads();
    for (int idx = tid; idx < 120; idx += 64) {
        int n = idx / 24, o = idx % 24;
        float a = out_proj_b[o];
        #pragma unroll
        for (int k = 0; k < 24; ++k) a += amix[n][k] * out_proj_w[o * 24 + k];
        aout[n][o] = x0[n][o] + a;
    }
    __syncthreads();
    if (tid < 5) {
        int n = tid;
        float m = 0.0f;
        #pragma unroll
        for (int k = 0; k < 24; ++k) m += aout[n][k];
        m *= (1.0f / 24.0f);
        float v = 0.0f;
        #pragma unroll
        for (int k = 0; k < 24; ++k) { float d = aout[n][k] - m; v += d * d; }
        v *= (1.0f / 24.0f);
        float inv = 1.0f / sqrtf(v + 1e-5f);
        #pragma unroll
        for (int k = 0; k < 24; ++k)
            x1[n][k] = (aout[n][k] - m) * inv * ln1_g[k] + ln1_b[k];
    }
    __syncthreads();
    for (int idx = tid; idx < 240; idx += 64) {
        int n = idx / 48, o = idx % 48;
        float a = ff1_b[o];
        #pragma unroll
        for (int k = 0; k < 24; ++k) a += x1[n][k] * ff1_w[o * 24 + k];
        ffh[n][o] = fmaxf(a, 0.0f);
    }
    __syncthreads();
    for (int idx = tid; idx < 120; idx += 64) {
        int n = idx / 24, o = idx % 24;
        float a = ff2_b[o];
        #pragma unroll
        for (int k = 0; k < 48; ++k) a += ffh[n][k] * ff2_w[o * 48 + k];
        ff2o[n][o] = x1[n][o] + a;
    }
    __syncthreads();
    if (tid < 5) {
        int n = tid;
        float m = 0.0f;
        #pragma unroll
        for (int k = 0; k < 24; ++k) m += ff2o[n][k];
        m *= (1.0f / 24.0f);
        float v = 0.0f;
        #pragma unroll
        for (int k = 0; k < 24; ++k) { float d = ff2o[n][k] - m; v += d * d; }
        v *= (1.0f / 24.0f);
        float inv = 1.0f / sqrtf(v + 1e-5f);
        #pragma unroll
        for (int k = 0; k < 24; ++k)
            hset[n][k] = (ff2o[n][k] - m) * inv * ln2_g[k] + ln2_b[k];
    }
    __syncthreads();
    for (int idx = tid; idx < 120; idx += 64) {
        int n = idx / 24, d = idx % 24;
        float s = hset[0][d] + hset[1][d] + hset[2][d] + hset[3][d] + hset[4][d];
        mo[n][d] = (s - hset[n][d]) * 0.25f;
    }
    if (tid < 20) {
        int i = tid / 4, jj = tid % 4;
        int j = jj + (jj >= i ? 1 : 0);
        float qo = 0.0f;
        #pragma unroll
        for (int k = 0; k < 6; ++k) qo += q[i][k] * q[j][k];
        pq[tid] = qo;
        float d2 = 0.0f;
        #pragma unroll
        for (int k = 0; k < 24; ++k) { float d = coord[i][k] - coord[j][k]; d2 += d * d; }
        pdist[tid] = (d2 > 0.0f) ? sqrtf(d2) : 0.0f;
    }
    __syncthreads();
    for (int idx = tid; idx < 200; idx += 64) {
        int p = idx / 10, c = idx % 10;
        int i = p / 4, jj = p % 4;
        int j = jj + (jj >= i ? 1 : 0);
        float a = rel1_b[c];
        const float* wr = rel1_w + c * 74;
        #pragma unroll
        for (int k = 0; k < 24; ++k) a += hset[i][k] * wr[k];
        #pragma unroll
        for (int k = 0; k < 24; ++k) a += hset[j][k] * wr[24 + k];
        #pragma unroll
        for (int k = 0; k < 24; ++k) a += fabsf(coord[i][k] - coord[j][k]) * wr[48 + k];
        a += pq[p] * wr[72];
        a += pdist[p] * wr[73];
        relh[p][c] = fmaxf(a, 0.0f);
    }
    __syncthreads();
    for (int idx = tid; idx < 200; idx += 64) {
        int p = idx / 10, c = idx % 10;
        float a = rel2_b[c];
        #pragma unroll
        for (int k = 0; k < 10; ++k) a += relh[p][k] * rel2_w[c * 10 + k];
        relo[p][c] = fmaxf(a, 0.0f);
    }
    __syncthreads();
    for (int idx = tid; idx < 50; idx += 64) {
        int i = idx / 10, c = idx % 10;
        float s = 0.0f, m = -1e30f;
        #pragma unroll
        for (int jj = 0; jj < 4; ++jj) {
            float v = relo[i * 4 + jj][c];
            s += v; m = fmaxf(m, v);
        }
        rmean[i][c] = s * 0.25f;
        rmax[i][c] = m;
    }
    __syncthreads();
    for (int idx = tid; idx < 730; idx += 64) {
        int n = idx / 146, k = idx % 146;
        float v;
        if (k < 24)       v = h0[n][k];
        else if (k < 48)  v = hset[n][k - 24];
        else if (k < 72)  v = center[n][k - 48];
        else if (k < 96)  v = coord[n][k - 72];
        else if (k < 120) v = fabsf(hset[n][k - 96] - mo[n][k - 96]);
        else if (k < 130) v = rmean[n][k - 120];
        else if (k < 140) v = rmax[n][k - 130];
        else              v = q[n][k - 140];
        sfeat[n][k] = v;
    }
    __syncthreads();
    for (int idx = tid; idx < 200; idx += 64) {
        int n = idx / 40, o = idx % 40;
        float a = s1_b[o];
        for (int k = 0; k < 146; ++k) a += sfeat[n][k] * s1_w[o * 146 + k];
        s1h[n][o] = fmaxf(a, 0.0f);
    }
    __syncthreads();
    if (tid < 5) {
        int n = tid;
        float a = s2_b[0];
        #pragma unroll
        for (int k = 0; k < 40; ++k) a += s1h[n][k] * s2_w[k];
        out[(size_t)b * 5 + n] = a;
    }
    if (tid < 30) {
        out[q_off + (size_t)b * 30 + tid] = q[tid / 6][tid % 6];
    }
}

extern "C" void kernel_launch(void* const* d_in, const int* in_sizes, int n_in,
                              void* d_out, int out_size, void* d_ws, size_t ws_size,
                              hipStream_t stream) {
    const int BN = in_sizes[0] / (64 * 64);   // B*5
    const int Bb = BN / 5;                    // B

    float* pooled = (float*)d_ws;             // [BN][16] fp32

    cnn_panel_kernel<<<BN, 256, 0, stream>>>(
        (const float*)d_in[0],
        (const float*)d_in[2], (const float*)d_in[3],
        (const float*)d_in[4], (const float*)d_in[5],
        (const float*)d_in[6], (const float*)d_in[7],
        pooled);

    head_kernel<<<Bb, 64, 0, stream>>>(
        pooled, (const float*)d_in[1],
        (const float*)d_in[8], (const float*)d_in[9],
        (const float*)d_in[10], (const float*)d_in[11],
        (const float*)d_in[12], (const float*)d_in[13],
        (const float*)d_in[14], (const float*)d_in[15],
        (const float*)d_in[16], (const float*)d_in[17],
        (const float*)d_in[18],
        (const float*)d_in[19], (const float*)d_in[20],
        (const float*)d_in[21], (const float*)d_in[22],
        (const float*)d_in[23], (const float*)d_in[24],
        (const float*)d_in[25], (const float*)d_in[26],
        (const float*)d_in[27], (const float*)d_in[28],
        (const float*)d_in[29], (const float*)d_in[30],
        (const float*)d_in[31], (const float*)d_in[32],
        (const float*)d_in[33], (const float*)d_in[34],
        (const float*)d_in[35], (const float*)d_in[36],
        (const float*)d_in[37], (const float*)d_in[38],
        (const float*)d_in[39], (const float*)d_in[40],
        (float*)d_out, BN);
}

// Round 7
// 431.634 us; speedup vs baseline: 1.4811x; 1.1046x over previous
//
#include <hip/hip_runtime.h>
#include <hip/hip_bf16.h>

// OddOneOutNet forward: B=1024, N=5, H=W=64, D=24, NK=6, META=16.
// Inputs fp32, output fp32, math fp32.
// Kernel A: per-panel TinyCNN, LDS 40,000 B (conv1 accumulates in regs so h1
//   aliases the dead input buffer) -> 4 blocks/CU (was 3).
// Kernel B: head, ONE WAVE PER BATCH ROW, wave-synchronous (no __syncthreads
//   after entry) — removes the 25-barrier serial chain that cost ~205 us.

// ---------------------------------------------------------------------------
// Kernel A. lds[10000] floats:
//   phase 1: inBuf[66*66]=4356 at offset 0
//   phase 2: h1[8][32][34]=8704 at offset 0 (aliases inBuf), h2[12][18][18]=1296 at 8704
// ---------------------------------------------------------------------------
__global__ __launch_bounds__(256, 4)
void cnn_panel_kernel(const float* __restrict__ xin,   // [BN,64,64]
                      const float* __restrict__ c1w, const float* __restrict__ c1b,
                      const float* __restrict__ c2w, const float* __restrict__ c2b,
                      const float* __restrict__ c3w, const float* __restrict__ c3b,
                      float* __restrict__ pooled)      // [BN,16] (ws)
{
    __shared__ float lds[10000];
    float* const inBuf = lds;          // 66*66, phase 1 only
    float* const h1    = lds;          // 8*32*34, phase 2 (aliases inBuf)
    float* const h2    = lds + 8704;   // 12*18*18

    const int tid = threadIdx.x;
    const int img = blockIdx.x;

    // ---- zero padded input buffer ----
    for (int i = tid; i < 66 * 66; i += 256) inBuf[i] = 0.0f;
    __syncthreads();

    // ---- load 64x64 panel into padded inBuf (float4) ----
    {
        const float4* xv = (const float4*)(xin + (size_t)img * 4096);
        for (int i = tid; i < 1024; i += 256) {
            float4 u = xv[i];
            int base = i << 2;
            int y = base >> 6, x = base & 63;
            float* dst = &inBuf[(y + 1) * 66 + (x + 1)];
            dst[0] = u.x; dst[1] = u.y; dst[2] = u.z; dst[3] = u.w;
        }
    }
    __syncthreads();

    // ---- conv1(1->8,3x3,SAME)+relu+maxpool2, accumulate in REGISTERS ----
    float c1out[4][8];
    #pragma unroll
    for (int p = 0; p < 4; ++p) {
        int pos = tid + (p << 8);
        int py = pos >> 5, px = pos & 31;
        float patch[4][4];
        #pragma unroll
        for (int dy = 0; dy < 4; ++dy)
            #pragma unroll
            for (int dx = 0; dx < 4; ++dx)
                patch[dy][dx] = inBuf[(2 * py + dy) * 66 + (2 * px + dx)];
        #pragma unroll
        for (int c = 0; c < 8; ++c) {
            float bb = c1b[c];
            float m = -1e30f;
            #pragma unroll
            for (int ay = 0; ay < 2; ++ay)
                #pragma unroll
                for (int ax = 0; ax < 2; ++ax) {
                    float acc = bb;
                    #pragma unroll
                    for (int ky = 0; ky < 3; ++ky)
                        #pragma unroll
                        for (int kx = 0; kx < 3; ++kx)
                            acc += patch[ay + ky][ax + kx] * c1w[c * 9 + ky * 3 + kx];
                    m = fmaxf(m, acc);
                }
            c1out[p][c] = fmaxf(m, 0.0f);
        }
    }
    __syncthreads();   // all inBuf reads done; safe to overwrite as h1

    // ---- write h1 interior + zero h1 x-pads + zero h2 ----
    #pragma unroll
    for (int p = 0; p < 4; ++p) {
        int pos = tid + (p << 8);
        int py = pos >> 5, px = pos & 31;
        #pragma unroll
        for (int c = 0; c < 8; ++c)
            h1[c * 1088 + py * 34 + (px + 1)] = c1out[p][c];
    }
    for (int i = tid; i < 512; i += 256) {
        int c = i >> 6, rest = i & 63;
        int y = rest >> 1, side = rest & 1;
        h1[c * 1088 + y * 34 + side * 33] = 0.0f;
    }
    for (int i = tid; i < 12 * 18 * 18; i += 256) h2[i] = 0.0f;
    __syncthreads();

    // ---- conv2(8->12)+relu+maxpool2 -> h2 interior [12][16][16] ----
    {
        int py = tid >> 4, px = tid & 15;
        float acc[12][4];
        #pragma unroll
        for (int c = 0; c < 12; ++c) {
            float bb = c2b[c];
            acc[c][0] = bb; acc[c][1] = bb; acc[c][2] = bb; acc[c][3] = bb;
        }
        for (int ci = 0; ci < 8; ++ci) {
            float patch[4][4];
            #pragma unroll
            for (int dy = 0; dy < 4; ++dy) {
                int r = 2 * py - 1 + dy;
                bool okr = (r >= 0) && (r < 32);
                const float* row = &h1[ci * 1088 + r * 34 + 2 * px];
                #pragma unroll
                for (int dx = 0; dx < 4; ++dx)
                    patch[dy][dx] = okr ? row[dx] : 0.0f;
            }
            #pragma unroll
            for (int c = 0; c < 12; ++c) {
                const float* wp = &c2w[(c * 8 + ci) * 9];
                #pragma unroll
                for (int ay = 0; ay < 2; ++ay)
                    #pragma unroll
                    for (int ax = 0; ax < 2; ++ax) {
                        float a = acc[c][ay * 2 + ax];
                        #pragma unroll
                        for (int ky = 0; ky < 3; ++ky)
                            #pragma unroll
                            for (int kx = 0; kx < 3; ++kx)
                                a += patch[ay + ky][ax + kx] * wp[ky * 3 + kx];
                        acc[c][ay * 2 + ax] = a;
                    }
            }
        }
        #pragma unroll
        for (int c = 0; c < 12; ++c) {
            float m = fmaxf(fmaxf(acc[c][0], acc[c][1]), fmaxf(acc[c][2], acc[c][3]));
            h2[c * 324 + (py + 1) * 18 + (px + 1)] = fmaxf(m, 0.0f);
        }
    }
    __syncthreads();

    // ---- conv3(12->16)+relu+mean -> pooled[img][16] ----
    {
        int y = tid >> 4, x = tid & 15;
        float acc[16];
        #pragma unroll
        for (int c = 0; c < 16; ++c) acc[c] = c3b[c];
        for (int ci = 0; ci < 12; ++ci) {
            float patch[3][3];
            #pragma unroll
            for (int dy = 0; dy < 3; ++dy)
                #pragma unroll
                for (int dx = 0; dx < 3; ++dx)
                    patch[dy][dx] = h2[ci * 324 + (y + dy) * 18 + (x + dx)];
            #pragma unroll
            for (int c = 0; c < 16; ++c) {
                const float* wp = &c3w[(c * 12 + ci) * 9];
                float a = acc[c];
                #pragma unroll
                for (int ky = 0; ky < 3; ++ky)
                    #pragma unroll
                    for (int kx = 0; kx < 3; ++kx)
                        a += patch[ky][kx] * wp[ky * 3 + kx];
                acc[c] = a;
            }
        }
        float* red = h1;  // h1 dead during conv3
        int lane = tid & 63, wave = tid >> 6;
        #pragma unroll
        for (int c = 0; c < 16; ++c) {
            float v = fmaxf(acc[c], 0.0f);
            v += __shfl_down(v, 32);
            v += __shfl_down(v, 16);
            v += __shfl_down(v, 8);
            v += __shfl_down(v, 4);
            v += __shfl_down(v, 2);
            v += __shfl_down(v, 1);
            if (lane == 0) red[c * 4 + wave] = v;
        }
        __syncthreads();
        if (tid < 16) {
            float s = red[tid * 4] + red[tid * 4 + 1] + red[tid * 4 + 2] + red[tid * 4 + 3];
            pooled[(size_t)img * 16 + tid] = s * (1.0f / 256.0f);
        }
    }
}

// ---------------------------------------------------------------------------
// Kernel B: head. 256-thread blocks, 4 waves, ONE WAVE PER BATCH ROW.
// Wave-synchronous: each wave owns S[wid]; NO __syncthreads after entry.
// LDS: 4 x 15,520 B = 62,080 B.
// ---------------------------------------------------------------------------
struct RowS {
    float ph[5][16], mt[5][16];
    float zc[5][20], zmh[5][12], zm[5][12];
    float p1h[5][24], h0[5][24];
    float archl[5][6], q[5][6];
    float center[5][24], coord[5][24], x0[5][24];
    float qkv[5][72];
    float attn[2][5][5];
    float amix[5][24], aout[5][24], x1[5][24];
    float ffh[5][48], ff2o[5][24], hset[5][24], mo[5][24];
    float pq[20], pdist[20];
    float relh[20][10], relo[20][10];
    float rmean[5][10], rmax[5][10];
    float sfeat[5][146];
    float s1h[5][40];
};

__global__ __launch_bounds__(256)
void head_kernel(const float* __restrict__ pooled,    // [B*5,16]
                 const float* __restrict__ meta,      // [B,5,16]
                 const float* __restrict__ enc_fc_w, const float* __restrict__ enc_fc_b,
                 const float* __restrict__ m1_w, const float* __restrict__ m1_b,
                 const float* __restrict__ m2_w, const float* __restrict__ m2_b,
                 const float* __restrict__ p1_w, const float* __restrict__ p1_b,
                 const float* __restrict__ p2_w, const float* __restrict__ p2_b,
                 const float* __restrict__ centers,
                 const float* __restrict__ arch_w, const float* __restrict__ arch_b,
                 const float* __restrict__ in_proj_w, const float* __restrict__ in_proj_b,
                 const float* __restrict__ out_proj_w, const float* __restrict__ out_proj_b,
                 const float* __restrict__ ln1_g, const float* __restrict__ ln1_b,
                 const float* __restrict__ ff1_w, const float* __restrict__ ff1_b,
                 const float* __restrict__ ff2_w, const float* __restrict__ ff2_b,
                 const float* __restrict__ ln2_g, const float* __restrict__ ln2_b,
                 const float* __restrict__ rel1_w, const float* __restrict__ rel1_b,
                 const float* __restrict__ rel2_w, const float* __restrict__ rel2_b,
                 const float* __restrict__ s1_w, const float* __restrict__ s1_b,
                 const float* __restrict__ s2_w, const float* __restrict__ s2_b,
                 float* __restrict__ out, int q_off, int Bb)
{
    __shared__ RowS S[4];

    const int tid  = threadIdx.x;
    const int wid  = tid >> 6;
    const int lane = tid & 63;
    const int row  = blockIdx.x * 4 + wid;
    if (row >= Bb) return;

    RowS& H = S[wid];

    for (int i = lane; i < 80; i += 64) ((float*)H.ph)[i] = pooled[(size_t)row * 80 + i];
    for (int i = lane; i < 80; i += 64) ((float*)H.mt)[i] = meta[(size_t)row * 80 + i];

    for (int idx = lane; idx < 100; idx += 64) {
        int n = idx / 20, o = idx % 20;
        float a = enc_fc_b[o];
        #pragma unroll
        for (int k = 0; k < 16; ++k) a += H.ph[n][k] * enc_fc_w[o * 16 + k];
        H.zc[n][o] = a;
    }
    for (int idx = lane; idx < 60; idx += 64) {
        int n = idx / 12, o = idx % 12;
        float a = m1_b[o];
        #pragma unroll
        for (int k = 0; k < 16; ++k) a += H.mt[n][k] * m1_w[o * 16 + k];
        H.zmh[n][o] = fmaxf(a, 0.0f);
    }
    for (int idx = lane; idx < 60; idx += 64) {
        int n = idx / 12, o = idx % 12;
        float a = m2_b[o];
        #pragma unroll
        for (int k = 0; k < 12; ++k) a += H.zmh[n][k] * m2_w[o * 12 + k];
        H.zm[n][o] = a;
    }
    for (int idx = lane; idx < 120; idx += 64) {
        int n = idx / 24, o = idx % 24;
        float a = p1_b[o];
        #pragma unroll
        for (int k = 0; k < 20; ++k) a += H.zc[n][k] * p1_w[o * 32 + k];
        #pragma unroll
        for (int k = 0; k < 12; ++k) a += H.zm[n][k] * p1_w[o * 32 + 20 + k];
        H.p1h[n][o] = fmaxf(a, 0.0f);
    }
    for (int idx = lane; idx < 120; idx += 64) {
        int n = idx / 24, o = idx % 24;
        float a = p2_b[o];
        #pragma unroll
        for (int k = 0; k < 24; ++k) a += H.p1h[n][k] * p2_w[o * 24 + k];
        H.h0[n][o] = a;
    }
    for (int idx = lane; idx < 30; idx += 64) {
        int n = idx / 6, o = idx % 6;
        float a = arch_b[o];
        #pragma unroll
        for (int k = 0; k < 24; ++k) a += H.h0[n][k] * arch_w[o * 24 + k];
        H.archl[n][o] = a;
    }
    if (lane < 5) {
        int n = lane;
        float m = H.archl[n][0];
        #pragma unroll
        for (int k = 1; k < 6; ++k) m = fmaxf(m, H.archl[n][k]);
        float e[6], s = 0.0f;
        #pragma unroll
        for (int k = 0; k < 6; ++k) { e[k] = __expf(H.archl[n][k] - m); s += e[k]; }
        float inv = 1.0f / s;
        #pragma unroll
        for (int k = 0; k < 6; ++k) H.q[n][k] = e[k] * inv;
    }
    for (int idx = lane; idx < 120; idx += 64) {
        int n = idx / 24, d = idx % 24;
        float a = 0.0f;
        #pragma unroll
        for (int k = 0; k < 6; ++k) a += H.q[n][k] * centers[k * 24 + d];
        H.center[n][d] = a;
        H.coord[n][d] = H.h0[n][d] - a;
        H.x0[n][d] = H.h0[n][d] + a;
    }
    for (int idx = lane; idx < 360; idx += 64) {
        int n = idx / 72, o = idx % 72;
        float a = in_proj_b[o];
        #pragma unroll
        for (int k = 0; k < 24; ++k) a += H.x0[n][k] * in_proj_w[o * 24 + k];
        H.qkv[n][o] = a;
    }
    if (lane < 10) {
        int h = lane / 5, i = lane % 5;
        const float scale = 0.28867513459481287f;  // 1/sqrt(12)
        float sc[5], m = -1e30f;
        for (int j = 0; j < 5; ++j) {
            float a = 0.0f;
            #pragma unroll
            for (int d = 0; d < 12; ++d) a += H.qkv[i][h * 12 + d] * H.qkv[j][24 + h * 12 + d];
            sc[j] = a * scale;
            m = fmaxf(m, sc[j]);
        }
        float s = 0.0f;
        #pragma unroll
        for (int j = 0; j < 5; ++j) { sc[j] = __expf(sc[j] - m); s += sc[j]; }
        float inv = 1.0f / s;
        #pragma unroll
        for (int j = 0; j < 5; ++j) H.attn[h][i][j] = sc[j] * inv;
    }
    for (int idx = lane; idx < 120; idx += 64) {
        int i = idx / 24, o = idx % 24;
        int h = o / 12, d = o % 12;
        float a = 0.0f;
        #pragma unroll
        for (int j = 0; j < 5; ++j) a += H.attn[h][i][j] * H.qkv[j][48 + h * 12 + d];
        H.amix[i][o] = a;
    }
    for (int idx = lane; idx < 120; idx += 64) {
        int n = idx / 24, o = idx % 24;
        float a = out_proj_b[o];
        #pragma unroll
        for (int k = 0; k < 24; ++k) a += H.amix[n][k] * out_proj_w[o * 24 + k];
        H.aout[n][o] = H.x0[n][o] + a;
    }
    if (lane < 5) {
        int n = lane;
        float m = 0.0f;
        #pragma unroll
        for (int k = 0; k < 24; ++k) m += H.aout[n][k];
        m *= (1.0f / 24.0f);
        float v = 0.0f;
        #pragma unroll
        for (int k = 0; k < 24; ++k) { float d = H.aout[n][k] - m; v += d * d; }
        v *= (1.0f / 24.0f);
        float inv = 1.0f / sqrtf(v + 1e-5f);
        #pragma unroll
        for (int k = 0; k < 24; ++k)
            H.x1[n][k] = (H.aout[n][k] - m) * inv * ln1_g[k] + ln1_b[k];
    }
    for (int idx = lane; idx < 240; idx += 64) {
        int n = idx / 48, o = idx % 48;
        float a = ff1_b[o];
        #pragma unroll
        for (int k = 0; k < 24; ++k) a += H.x1[n][k] * ff1_w[o * 24 + k];
        H.ffh[n][o] = fmaxf(a, 0.0f);
    }
    for (int idx = lane; idx < 120; idx += 64) {
        int n = idx / 24, o = idx % 24;
        float a = ff2_b[o];
        #pragma unroll
        for (int k = 0; k < 48; ++k) a += H.ffh[n][k] * ff2_w[o * 48 + k];
        H.ff2o[n][o] = H.x1[n][o] + a;
    }
    if (lane < 5) {
        int n = lane;
        float m = 0.0f;
        #pragma unroll
        for (int k = 0; k < 24; ++k) m += H.ff2o[n][k];
        m *= (1.0f / 24.0f);
        float v = 0.0f;
        #pragma unroll
        for (int k = 0; k < 24; ++k) { float d = H.ff2o[n][k] - m; v += d * d; }
        v *= (1.0f / 24.0f);
        float inv = 1.0f / sqrtf(v + 1e-5f);
        #pragma unroll
        for (int k = 0; k < 24; ++k)
            H.hset[n][k] = (H.ff2o[n][k] - m) * inv * ln2_g[k] + ln2_b[k];
    }
    for (int idx = lane; idx < 120; idx += 64) {
        int n = idx / 24, d = idx % 24;
        float s = H.hset[0][d] + H.hset[1][d] + H.hset[2][d] + H.hset[3][d] + H.hset[4][d];
        H.mo[n][d] = (s - H.hset[n][d]) * 0.25f;
    }
    if (lane < 20) {
        int i = lane / 4, jj = lane % 4;
        int j = jj + (jj >= i ? 1 : 0);
        float qo = 0.0f;
        #pragma unroll
        for (int k = 0; k < 6; ++k) qo += H.q[i][k] * H.q[j][k];
        H.pq[lane] = qo;
        float d2 = 0.0f;
        #pragma unroll
        for (int k = 0; k < 24; ++k) { float d = H.coord[i][k] - H.coord[j][k]; d2 += d * d; }
        H.pdist[lane] = (d2 > 0.0f) ? sqrtf(d2) : 0.0f;
    }
    for (int idx = lane; idx < 200; idx += 64) {
        int p = idx / 10, c = idx % 10;
        int i = p / 4, jj = p % 4;
        int j = jj + (jj >= i ? 1 : 0);
        float a = rel1_b[c];
        const float* wr = rel1_w + c * 74;
        #pragma unroll
        for (int k = 0; k < 24; ++k) a += H.hset[i][k] * wr[k];
        #pragma unroll
        for (int k = 0; k < 24; ++k) a += H.hset[j][k] * wr[24 + k];
        #pragma unroll
        for (int k = 0; k < 24; ++k) a += fabsf(H.coord[i][k] - H.coord[j][k]) * wr[48 + k];
        a += H.pq[p] * wr[72];
        a += H.pdist[p] * wr[73];
        H.relh[p][c] = fmaxf(a, 0.0f);
    }
    for (int idx = lane; idx < 200; idx += 64) {
        int p = idx / 10, c = idx % 10;
        float a = rel2_b[c];
        #pragma unroll
        for (int k = 0; k < 10; ++k) a += H.relh[p][k] * rel2_w[c * 10 + k];
        H.relo[p][c] = fmaxf(a, 0.0f);
    }
    for (int idx = lane; idx < 50; idx += 64) {
        int i = idx / 10, c = idx % 10;
        float s = 0.0f, m = -1e30f;
        #pragma unroll
        for (int jj = 0; jj < 4; ++jj) {
            float v = H.relo[i * 4 + jj][c];
            s += v; m = fmaxf(m, v);
        }
        H.rmean[i][c] = s * 0.25f;
        H.rmax[i][c] = m;
    }
    for (int idx = lane; idx < 730; idx += 64) {
        int n = idx / 146, k = idx % 146;
        float v;
        if (k < 24)       v = H.h0[n][k];
        else if (k < 48)  v = H.hset[n][k - 24];
        else if (k < 72)  v = H.center[n][k - 48];
        else if (k < 96)  v = H.coord[n][k - 72];
        else if (k < 120) v = fabsf(H.hset[n][k - 96] - H.mo[n][k - 96]);
        else if (k < 130) v = H.rmean[n][k - 120];
        else if (k < 140) v = H.rmax[n][k - 130];
        else              v = H.q[n][k - 140];
        H.sfeat[n][k] = v;
    }
    for (int idx = lane; idx < 200; idx += 64) {
        int n = idx / 40, o = idx % 40;
        float a = s1_b[o];
        #pragma unroll 8
        for (int k = 0; k < 146; ++k) a += H.sfeat[n][k] * s1_w[o * 146 + k];
        H.s1h[n][o] = fmaxf(a, 0.0f);
    }
    if (lane < 5) {
        int n = lane;
        float a = s2_b[0];
        #pragma unroll
        for (int k = 0; k < 40; ++k) a += H.s1h[n][k] * s2_w[k];
        out[(size_t)row * 5 + n] = a;
    }
    if (lane < 30) {
        out[q_off + (size_t)row * 30 + lane] = H.q[lane / 6][lane % 6];
    }
}

extern "C" void kernel_launch(void* const* d_in, const int* in_sizes, int n_in,
                              void* d_out, int out_size, void* d_ws, size_t ws_size,
                              hipStream_t stream) {
    const int BN = in_sizes[0] / (64 * 64);   // B*5
    const int Bb = BN / 5;                    // B

    float* pooled = (float*)d_ws;             // [BN][16] fp32

    cnn_panel_kernel<<<BN, 256, 0, stream>>>(
        (const float*)d_in[0],
        (const float*)d_in[2], (const float*)d_in[3],
        (const float*)d_in[4], (const float*)d_in[5],
        (const float*)d_in[6], (const float*)d_in[7],
        pooled);

    head_kernel<<<(Bb + 3) / 4, 256, 0, stream>>>(
        pooled, (const float*)d_in[1],
        (const float*)d_in[8], (const float*)d_in[9],
        (const float*)d_in[10], (const float*)d_in[11],
        (const float*)d_in[12], (const float*)d_in[13],
        (const float*)d_in[14], (const float*)d_in[15],
        (const float*)d_in[16], (const float*)d_in[17],
        (const float*)d_in[18],
        (const float*)d_in[19], (const float*)d_in[20],
        (const float*)d_in[21], (const float*)d_in[22],
        (const float*)d_in[23], (const float*)d_in[24],
        (const float*)d_in[25], (const float*)d_in[26],
        (const float*)d_in[27], (const float*)d_in[28],
        (const float*)d_in[29], (const float*)d_in[30],
        (const float*)d_in[31], (const float*)d_in[32],
        (const float*)d_in[33], (const float*)d_in[34],
        (const float*)d_in[35], (const float*)d_in[36],
        (const float*)d_in[37], (const float*)d_in[38],
        (const float*)d_in[39], (const float*)d_in[40],
        (float*)d_out, BN, Bb);
}